// Round 16
// baseline (539.904 us; speedup 1.0000x reference)
//
#include <hip/hip_runtime.h>
#include <stdint.h>

#define SEQ   2048
#define BATCH 2
#define HD    4096
#define NH    32
#define NKV   2
#define HDIM  128
#define NT    (SEQ*BATCH)   // 4096 tokens
#define KVC   (NKV*HDIM)    // 256

typedef short  bf16x8 __attribute__((ext_vector_type(8)));
typedef short  sh4    __attribute__((ext_vector_type(4)));
typedef float  f32x4  __attribute__((ext_vector_type(4)));
typedef float  f32x16 __attribute__((ext_vector_type(16)));

__device__ __forceinline__ float bf2f(unsigned short u){
  union { unsigned int i; float f; } v; v.i = ((unsigned int)u) << 16; return v.f;
}
__device__ __forceinline__ unsigned short f2bf(float f){
  union { float f; unsigned int i; } v; v.f = f;
  unsigned int r = v.i + 0x7FFFu + ((v.i >> 16) & 1u);
  return (unsigned short)(r >> 16);
}
// pack 2 f32 -> 2 bf16 in one u32 (low = lo, high = hi)
__device__ __forceinline__ unsigned int cvtpk_bf16(float lo, float hi){
  unsigned int r;
  asm("v_cvt_pk_bf16_f32 %0, %1, %2" : "=v"(r) : "v"(lo), "v"(hi));
  return r;
}
// a[32:63] <-> b[0:31]
__device__ __forceinline__ void plane_swap(unsigned int &a, unsigned int &b){
  asm("v_permlane32_swap_b32 %0, %1" : "+v"(a), "+v"(b));
}
// Build PV B-frag (bf16x8) for one 16-k slice from 8 exp'd P values.
__device__ __forceinline__ bf16x8 mk_pf(float a0f,float a1f,float a2f,float a3f,
                                        float b0f,float b1f,float b2f,float b3f){
  unsigned int a0 = cvtpk_bf16(a0f, a1f);
  unsigned int a1 = cvtpk_bf16(a2f, a3f);
  unsigned int b0 = cvtpk_bf16(b0f, b1f);
  unsigned int b1 = cvtpk_bf16(b2f, b3f);
  plane_swap(a0, b0);
  plane_swap(a1, b1);
  union { unsigned int u[4]; bf16x8 h; } u;
  u.u[0] = a0; u.u[1] = a1; u.u[2] = b0; u.u[3] = b1;
  return u.h;
}

// async global->LDS, 16B per lane; LDS dest is wave-uniform base + lane*16
__device__ __forceinline__ void gload_lds16(const void* g, void* lds){
  __builtin_amdgcn_global_load_lds(
      (const __attribute__((address_space(1))) unsigned int*)(size_t)g,
      (__attribute__((address_space(3))) unsigned int*)(unsigned int)(size_t)lds,
      16, 0, 0);
}

__device__ __forceinline__ void BARRIER(){
  __builtin_amdgcn_sched_barrier(0);
  asm volatile("" ::: "memory");
  __builtin_amdgcn_s_barrier();
  asm volatile("" ::: "memory");
  __builtin_amdgcn_sched_barrier(0);
}
#define VMCNT(N) do { asm volatile("s_waitcnt vmcnt(" #N ")" ::: "memory"); \
                      __builtin_amdgcn_sched_barrier(0); } while(0)

// ---------------- cast fp32 -> bf16 (vectorized) ----------------
__global__ void k_cast(const float* __restrict__ in, unsigned short* __restrict__ out, int n4){
  int i = blockIdx.x * blockDim.x + threadIdx.x;
  if (i >= n4) return;
  float4 v = ((const float4*)in)[i];
  ushort4 o; o.x = f2bf(v.x); o.y = f2bf(v.y); o.z = f2bf(v.z); o.w = f2bf(v.w);
  ((ushort4*)out)[i] = o;
}

// ---------------- W (KxN fp32) -> W^T (NxK bf16), LDS tiled ----------------
__global__ void k_transpose(const float* __restrict__ W, unsigned short* __restrict__ WT,
                            int K, int N){
  __shared__ float t[32][33];
  int n0 = blockIdx.x * 32, k0 = blockIdx.y * 32;
  int tx = threadIdx.x, ty = threadIdx.y;
  t[ty][tx] = W[(size_t)(k0 + ty) * N + n0 + tx];
  __syncthreads();
  WT[(size_t)(n0 + ty) * K + k0 + tx] = f2bf(t[tx][ty]);
}

// ---------------- GEMM (m97 128x128) for small-N projections ----------------
// optional split bias: col < bsplit -> bias[col], else bias2[col-bsplit]
template<bool OUTF32>
__global__ __launch_bounds__(256) void k_gemm(
    const unsigned short* __restrict__ A,
    const unsigned short* __restrict__ BT,
    const float* __restrict__ bias,
    const float* __restrict__ bias2, int bsplit,
    void* __restrict__ C, int M, int N, int K)
{
  __shared__ unsigned short As[128*32];
  __shared__ unsigned short Bs[128*32];
  const int tid  = threadIdx.x;
  const int lane = tid & 63;
  const int w    = tid >> 6;
  const int l4   = lane >> 4, l15 = lane & 15;
  const int wm   = (w >> 1) * 64, wn = (w & 1) * 64;
  const size_t bm = (size_t)blockIdx.y * 128, bn = (size_t)blockIdx.x * 128;

  f32x4 acc[4][4] = {};
  const int scol = (lane & 3) * 8;

  for (int k0 = 0; k0 < K; k0 += 32) {
    #pragma unroll
    for (int j = 0; j < 2; ++j) {
      const int r = w*32 + j*16 + (lane >> 2);
      gload_lds16(A  + (bm + r) * (size_t)K + k0 + scol, As + (size_t)(w*32 + j*16) * 32);
      gload_lds16(BT + (bn + r) * (size_t)K + k0 + scol, Bs + (size_t)(w*32 + j*16) * 32);
    }
    __syncthreads();
    bf16x8 af[4], bfr[4];
    #pragma unroll
    for (int m = 0; m < 4; ++m)
      af[m] = *(const bf16x8*)(As + (wm + m*16 + l15)*32 + l4*8);
    #pragma unroll
    for (int n = 0; n < 4; ++n)
      bfr[n] = *(const bf16x8*)(Bs + (wn + n*16 + l15)*32 + l4*8);
    #pragma unroll
    for (int m = 0; m < 4; ++m)
      #pragma unroll
      for (int n = 0; n < 4; ++n)
        acc[m][n] = __builtin_amdgcn_mfma_f32_16x16x32_bf16(af[m], bfr[n], acc[m][n], 0, 0, 0);
    __syncthreads();
  }

  #pragma unroll
  for (int n = 0; n < 4; ++n) {
    const size_t col = bn + wn + n*16 + l15;
    float badd = 0.0f;
    if (bias) badd = (bias2 && (int)col >= bsplit) ? bias2[col - bsplit] : bias[col];
    #pragma unroll
    for (int m = 0; m < 4; ++m) {
      const size_t row0 = bm + wm + m*16 + l4*4;
      #pragma unroll
      for (int r = 0; r < 4; ++r) {
        float v = acc[m][n][r] + badd;
        if (OUTF32) ((float*)C)[(row0 + r) * (size_t)N + col] = v;
        else ((unsigned short*)C)[(row0 + r) * (size_t)N + col] = f2bf(v);
      }
    }
  }
}

// ---------------- 256x256 8-phase GEMM (T2+T3+T4+T5), K multiple of 128 ----------------
// MODE 0: bf16 out to C (ld N). MODE 1: f32 out to C (ld N).
template<int MODE>
__global__ __launch_bounds__(512, 2) void k_gemm256(
    const unsigned short* __restrict__ A,
    const unsigned short* __restrict__ BT,
    const float* __restrict__ bias,
    void* __restrict__ C,
    int M, int N, int K)
{
  __shared__ __attribute__((aligned(16))) unsigned short As[2][16384];
  __shared__ __attribute__((aligned(16))) unsigned short Bs[2][16384];
  const int tid  = threadIdx.x;
  const int lane = tid & 63;
  const int w    = tid >> 6;
  const int c    = lane & 15, g = lane >> 4;
  const int wm   = w >> 2, wn = w & 3;

  // XCD-aware mapping. For the 16x16 grid: each XCD (bid%8) owns a 4x8
  // rectangle of tiles -> per-XCD working set 8MB A + 16MB B.
  const int nwg = (int)(gridDim.x * gridDim.y);
  int bid = (int)(blockIdx.y * gridDim.x + blockIdx.x);
  int bx, by;
  if (gridDim.x == 16 && gridDim.y == 16) {
    const int k = bid & 7, cc = bid >> 3;     // XCD id, chunk index 0..31
    by = (k >> 1) * 4 + (cc >> 3);
    bx = (k & 1) * 8 + (cc & 7);
  } else {
    if ((nwg & 7) == 0) bid = (bid & 7) * (nwg >> 3) + (bid >> 3);
    bx = bid % (int)gridDim.x;
    by = bid / (int)gridDim.x;
  }
  const size_t bm = (size_t)by * 256, bn = (size_t)bx * 256;

  const char* Ab = (const char*)(A  + bm * (size_t)K);
  const char* Bb = (const char*)(BT + bn * (size_t)K);
  const size_t Kb2 = (size_t)K * 2;
  const int cswz = (c & 7) << 4;

  f32x4 acc[8][4] = {};
  bf16x8 af[4][2], bfr[4][2];

#define STAGE_A(bi, h, k0) do { \
    _Pragma("unroll") \
    for (int _j = 0; _j < 2; ++_j) { \
      const int _i = _j*512 + tid; \
      const int _row = (h)*128 + (_i >> 3); \
      const int _ch  = _i & 7; \
      gload_lds16(Ab + (size_t)_row * Kb2 + (size_t)(k0)*2 + ((_ch*16) ^ ((_row & 7) << 4)), \
                  (char*)As[bi] + (h)*16384 + _j*8192 + w*1024); \
    } } while(0)
#define STAGE_B(bi, h, k0) do { \
    _Pragma("unroll") \
    for (int _j = 0; _j < 2; ++_j) { \
      const int _i = _j*512 + tid; \
      const int _row = (h)*128 + (_i >> 3); \
      const int _ch  = _i & 7; \
      gload_lds16(Bb + (size_t)_row * Kb2 + (size_t)(k0)*2 + ((_ch*16) ^ ((_row & 7) << 4)), \
                  (char*)Bs[bi] + (h)*16384 + _j*8192 + w*1024); \
    } } while(0)
#define LDA(bi, mg) do { \
    _Pragma("unroll") \
    for (int _m = 0; _m < 4; ++_m) { \
      const char* _p = (const char*)As[bi] + (size_t)(((mg)*128 + _m*32 + wm*16 + c) * 128); \
      af[_m][0] = *(const bf16x8*)(_p + (( 0 + g*16) ^ cswz)); \
      af[_m][1] = *(const bf16x8*)(_p + ((64 + g*16) ^ cswz)); \
    } } while(0)
#define LDB(bi, ng) do { \
    _Pragma("unroll") \
    for (int _n = 0; _n < 2; ++_n) { \
      const char* _p = (const char*)Bs[bi] + (size_t)((((ng)*2+_n)*64 + wn*16 + c) * 128); \
      bfr[(ng)*2+_n][0] = *(const bf16x8*)(_p + (( 0 + g*16) ^ cswz)); \
      bfr[(ng)*2+_n][1] = *(const bf16x8*)(_p + ((64 + g*16) ^ cswz)); \
    } } while(0)
#define MFMA16(mg, ng) do { \
    __builtin_amdgcn_s_setprio(1); \
    _Pragma("unroll") \
    for (int _m = 0; _m < 4; ++_m) \
      _Pragma("unroll") \
      for (int _n = 0; _n < 2; ++_n) { \
        acc[(mg)*4+_m][(ng)*2+_n] = __builtin_amdgcn_mfma_f32_16x16x32_bf16( \
            af[_m][0], bfr[(ng)*2+_n][0], acc[(mg)*4+_m][(ng)*2+_n], 0, 0, 0); \
        acc[(mg)*4+_m][(ng)*2+_n] = __builtin_amdgcn_mfma_f32_16x16x32_bf16( \
            af[_m][1], bfr[(ng)*2+_n][1], acc[(mg)*4+_m][(ng)*2+_n], 0, 0, 0); \
      } \
    __builtin_amdgcn_s_setprio(0); \
  } while(0)

  STAGE_A(0, 0, 0);
  STAGE_B(0, 0, 0);
  STAGE_B(0, 1, 0);
  STAGE_A(0, 1, 0);
  STAGE_A(1, 0, 64);
  STAGE_B(1, 0, 64);
  VMCNT(8);
  BARRIER();

  const int niter = K >> 7;
  for (int it = 0; it < niter; ++it) {
    const int kb = it*128 + 64;
    int k2 = it*128 + 128; if (k2 >= K) k2 = 0;
    int k3 = it*128 + 192; if (k3 >= K) k3 = 0;
    // p1
    LDA(0, 0); LDB(0, 0);
    STAGE_A(1, 1, kb);
    BARRIER();
    MFMA16(0, 0);
    VMCNT(6);
    BARRIER();
    // p2
    LDB(0, 1);
    STAGE_B(1, 1, kb);
    BARRIER();
    MFMA16(0, 1);
    BARRIER();
    // p3
    LDA(0, 1);
    STAGE_A(0, 0, k2);
    BARRIER();
    MFMA16(1, 0);
    BARRIER();
    // p4
    STAGE_B(0, 0, k2);
    BARRIER();
    MFMA16(1, 1);
    VMCNT(8);
    BARRIER();
    // p5
    LDA(1, 0); LDB(1, 0);
    STAGE_A(0, 1, k2);
    BARRIER();
    MFMA16(0, 0);
    VMCNT(6);
    BARRIER();
    // p6
    LDB(1, 1);
    STAGE_B(0, 1, k2);
    BARRIER();
    MFMA16(0, 1);
    BARRIER();
    // p7
    LDA(1, 1);
    STAGE_A(1, 0, k3);
    BARRIER();
    MFMA16(1, 0);
    BARRIER();
    // p8
    STAGE_B(1, 0, k3);
    BARRIER();
    MFMA16(1, 1);
    VMCNT(8);
    BARRIER();
  }

  #pragma unroll
  for (int m = 0; m < 8; ++m) {
    const size_t row0 = bm + m*32 + wm*16 + g*4;
    #pragma unroll
    for (int n = 0; n < 4; ++n) {
      const int col = (int)bn + n*64 + wn*16 + c;
      const float badd = bias ? bias[col] : 0.0f;
      #pragma unroll
      for (int r = 0; r < 4; ++r) {
        float v = acc[m][n][r] + badd;
        if (MODE == 1) ((float*)C)[(row0 + r) * (size_t)N + col] = v;
        else ((unsigned short*)C)[(row0 + r) * (size_t)N + col] = f2bf(v);
      }
    }
  }
#undef STAGE_A
#undef STAGE_B
#undef LDA
#undef LDB
#undef MFMA16
}

// ---------------- RoPE + layout: [tok][ldin] -> [b][slab][s][d], optional scale ----------------
__global__ void k_rope(const unsigned short* __restrict__ In, const float* __restrict__ rope,
                       unsigned short* __restrict__ Out, int ldin, int ncols, int nslab,
                       int psh, float sc)
{
  int idx = blockIdx.x * 256 + threadIdx.x;
  int npair = ncols >> 1;
  if (idx >= NT * npair) return;
  int t = idx >> psh, pr = idx & (npair - 1);
  int colp = pr * 2, h = colp >> 7, d = colp & 127;
  int s = t >> 1, b = t & 1;
  float x0 = bf2f(In[(size_t)t * ldin + colp]);
  float x1 = bf2f(In[(size_t)t * ldin + colp + 1]);
  float o0 = x0, o1 = x1;
  if (d < 64) {
    int i2 = d >> 1;
    float cr = rope[((size_t)s * 32 + i2) * 2 + 0];
    float ci = rope[((size_t)s * 32 + i2) * 2 + 1];
    o0 = x0 * cr - x1 * ci;
    o1 = x1 * cr + x0 * ci;
  }
  size_t dst = ((size_t)(b * nslab + h) * SEQ + s) * HDIM + d;
  Out[dst]     = f2bf(o0 * sc);
  Out[dst + 1] = f2bf(o1 * sc);
}

// ---------------- V: [tok][ld] (256 cols) -> V^T [b][kv][d][s] ----------------
__global__ void k_vt(const unsigned short* __restrict__ In, int ld,
                     unsigned short* __restrict__ Out){
  int idx = blockIdx.x * 256 + threadIdx.x;
  if (idx >= NT * KVC) return;
  int t = idx >> 8, cp = idx & 255;
  int kv = cp >> 7, d = cp & 127;
  int s = t >> 1, b = t & 1;
  Out[((size_t)(b * NKV + kv) * HDIM + d) * SEQ + s] = In[(size_t)t * ld + cp];
}

// ---------------- causal flash attention: 32x32 MFMA, in-register softmax ----------------
// 4 waves/block, 32 q-rows/wave (QBLK=128), KVBLK=64. Swapped QK^T, T12/T13.
// K double-buffered (Ks[2], prefetch-ahead-1); V single-buffer staged at step top
// (ages under QK^T+softmax). Counted waits: mid-step VMCNT(4) retires V (K's 4
// loads are newer), end VMCNT(0) retires the aged K prefetch. LDS 48KB -> still
// 3 blocks/CU (VGPR-limited). launch_bounds(256,2): ~96 VGPR + 64 acc on the
// unified file; (256,4) caps at 128 regs and spills acc (r14: 3x slower).
__global__ __launch_bounds__(256, 2) void k_attn(
    const unsigned short* __restrict__ Q,    // [b][h][s][d], pre-scaled log2e/sqrt(d)
    const unsigned short* __restrict__ Kk,   // [b][kv][s][d]
    const unsigned short* __restrict__ Vt,   // [b][kv][d][s]
    unsigned short* __restrict__ Ctx)        // [tok][4096]
{
  const int tid  = threadIdx.x;
  const int lane = tid & 63;
  const int w    = tid >> 6;
  const int l31  = lane & 31;                // q within wave tile; also t/d row idx
  const int hi   = lane >> 5;
  const int bh = (int)blockIdx.x;            // bh on x (fast dim)
  const int b = bh >> 5, h = bh & 31;
  const int qb = (int)(gridDim.y - 1 - blockIdx.y);  // big tiles dispatched first
  const int qw0 = qb * 128 + w * 32;

  const unsigned short* Qb = Q  + ((size_t)(b * NH  + h)        * SEQ + qw0) * HDIM;
  const char* Kb = (const char*)(Kk + ((size_t)(b * NKV + (h >> 4)) * SEQ) * HDIM);
  const char* Vb = (const char*)(Vt + ((size_t)(b * NKV + (h >> 4)) * HDIM) * SEQ);

  __shared__ unsigned short Ks[2][64*128];    // K tiles [64 t][128 d], swizzled 256B rows
  __shared__ unsigned short Vs[128*64];       // V^T tile [128 d][64 t], swizzled 128B rows

  bf16x8 qf[8];
  #pragma unroll
  for (int kk = 0; kk < 8; ++kk)
    qf[kk] = *(const bf16x8*)(Qb + (size_t)l31 * HDIM + kk*16 + hi*8);

  f32x16 of0 = {}, of1 = {}, of2 = {}, of3 = {};
  float mrun = -1e30f, lrun = 0.0f;
  const int qmax = qw0 + 31;
  const int qg   = qw0 + l31;
  const int tblk = qb * 128 + 128;

  const int kr = lane >> 4, kc = lane & 15;   // K: 4 rows x 16 chunks
  const int vr = lane >> 3, vc = lane & 7;    // V: 8 rows x 8 chunks
  const int rswzK = (l31 & 15) << 4;          // K read-side XOR (4-bit)
  const int rswzV = (l31 & 7) << 4;           // V read-side XOR (3-bit)

  // prologue: stage K(0) into Ks[0]
  #pragma unroll
  for (int j = 0; j < 4; ++j) {
    const int r = w*16 + j*4 + kr;
    gload_lds16(Kb + (size_t)r * 256 + ((kc*16) ^ ((r & 15) << 4)),
                (char*)Ks[0] + (w*16 + j*4) * 256);
  }
  VMCNT(0);
  BARRIER();

  int cur = 0;
  for (int t0 = 0; t0 < tblk; t0 += 64) {
    // next K tile (clamped on last iter: harmless re-stage, keeps flow uniform)
    const int tn = (t0 + 64 < tblk) ? (t0 + 64) : t0;

    // ---- stage V(t0) FIRST (older in vmcnt FIFO) ----
    #pragma unroll
    for (int j = 0; j < 4; ++j) {
      const int d = w*32 + j*8 + vr;
      gload_lds16(Vb + (size_t)d * (SEQ*2) + (size_t)t0*2 + ((vc*16) ^ ((d & 7) << 4)),
                  (char*)Vs + (w*32 + j*8) * 128);
    }
    // ---- stage K(tn) into the other buffer (prefetch-ahead-1) ----
    #pragma unroll
    for (int j = 0; j < 4; ++j) {
      const int r = w*16 + j*4 + kr;
      gload_lds16(Kb + (size_t)(tn + r) * 256 + ((kc*16) ^ ((r & 15) << 4)),
                  (char*)Ks[cur ^ 1] + (w*16 + j*4) * 256);
    }

    const char* Kcur = (const char*)Ks[cur];
    const bool active = (t0 <= qmax);
    const bool act1   = (t0 + 32 <= qmax);
    bf16x8 pf0, pf1, pf2, pf3;

    if (active) {
      // ---- QK^T from Ks[cur] (already resident — no wait) ----
      f32x16 s0 = {};
      #pragma unroll
      for (int kk = 0; kk < 8; ++kk) {
        bf16x8 kf = *(const bf16x8*)(Kcur + l31*256 + ((kk*32 + hi*16) ^ rswzK));
        s0 = __builtin_amdgcn_mfma_f32_32x32x16_bf16(kf, qf[kk], s0, 0, 0, 0);
      }
      const int qh0 = qg - t0 - 4*hi;
      if (t0 + 31 > qw0) {
        #pragma unroll
        for (int r = 0; r < 16; ++r) {
          const int tc = (r & 3) + 8*(r >> 2);
          if (tc > qh0) s0[r] = -1e30f;
        }
      }
      f32x16 s1 = {};
      if (act1) {
        #pragma unroll
        for (int kk = 0; kk < 8; ++kk) {
          bf16x8 kf = *(const bf16x8*)(Kcur + (32 + l31)*256 + ((kk*32 + hi*16) ^ rswzK));
          s1 = __builtin_amdgcn_mfma_f32_32x32x16_bf16(kf, qf[kk], s1, 0, 0, 0);
        }
        if (t0 + 63 > qw0) {
          const int qh1 = qh0 - 32;
          #pragma unroll
          for (int r = 0; r < 16; ++r) {
            const int tc = (r & 3) + 8*(r >> 2);
            if (tc > qh1) s1[r] = -1e30f;
          }
        }
      }
      // ---- in-register online softmax (exp2 domain), q = lane&31 ----
      float mloc = s0[0];
      #pragma unroll
      for (int r = 1; r < 16; ++r) mloc = fmaxf(mloc, s0[r]);
      if (act1) {
        #pragma unroll
        for (int r = 0; r < 16; ++r) mloc = fmaxf(mloc, s1[r]);
      }
      mloc = fmaxf(mloc, __shfl_xor(mloc, 32));
      if (!__all(mloc - mrun <= 8.0f)) {            // T13 defer-max
        const float mn = fmaxf(mrun, mloc);
        const float al = exp2f(mrun - mn);
        mrun = mn;
        lrun *= al;
        of0 *= al; of1 *= al; of2 *= al; of3 *= al;
      }
      float ps = 0.0f;
      float p0[16];
      #pragma unroll
      for (int r = 0; r < 16; ++r) { p0[r] = exp2f(s0[r] - mrun); ps += p0[r]; }
      pf0 = mk_pf(p0[0],p0[1],p0[2],p0[3],   p0[4],p0[5],p0[6],p0[7]);
      pf1 = mk_pf(p0[8],p0[9],p0[10],p0[11], p0[12],p0[13],p0[14],p0[15]);
      if (act1) {
        float p1[16];
        #pragma unroll
        for (int r = 0; r < 16; ++r) { p1[r] = exp2f(s1[r] - mrun); ps += p1[r]; }
        pf2 = mk_pf(p1[0],p1[1],p1[2],p1[3],   p1[4],p1[5],p1[6],p1[7]);
        pf3 = mk_pf(p1[8],p1[9],p1[10],p1[11], p1[12],p1[13],p1[14],p1[15]);
      }
      ps += __shfl_xor(ps, 32);
      lrun += ps;
    }

    // V guaranteed in LDS: K's 4 loads are the only newer ones -> vmcnt(4).
    VMCNT(4);
    BARRIER();

    if (active) {
      // ---- PV: O^T[d][q] += V^T-frag(A) x P-frag(B) ----
#define PVDT(ofv, dt) do { \
        const char* _vrow = (const char*)Vs + (size_t)(((dt)*32 + l31) * 128); \
        bf16x8 _v0 = *(const bf16x8*)(_vrow + (( 0 + hi*16) ^ rswzV)); \
        bf16x8 _v1 = *(const bf16x8*)(_vrow + ((32 + hi*16) ^ rswzV)); \
        ofv = __builtin_amdgcn_mfma_f32_32x32x16_bf16(_v0, pf0, ofv, 0, 0, 0); \
        ofv = __builtin_amdgcn_mfma_f32_32x32x16_bf16(_v1, pf1, ofv, 0, 0, 0); \
        if (act1) { \
          bf16x8 _v2 = *(const bf16x8*)(_vrow + ((64 + hi*16) ^ rswzV)); \
          bf16x8 _v3 = *(const bf16x8*)(_vrow + ((96 + hi*16) ^ rswzV)); \
          ofv = __builtin_amdgcn_mfma_f32_32x32x16_bf16(_v2, pf2, ofv, 0, 0, 0); \
          ofv = __builtin_amdgcn_mfma_f32_32x32x16_bf16(_v3, pf3, ofv, 0, 0, 0); \
        } } while(0)
      PVDT(of0, 0);
      PVDT(of1, 1);
      PVDT(of2, 2);
      PVDT(of3, 3);
#undef PVDT
    }

    // drain the aged K(tn) prefetch; barrier orders PV reads before next V-stage
    VMCNT(0);
    BARRIER();
    cur ^= 1;
  }

  // ---- epilogue: O^T -> Ctx. row s = qg; d = dt*32 + trow ----
  const float inv = 1.0f / lrun;
  unsigned short* Crow = Ctx + ((size_t)(qg * BATCH + b)) * HD + (size_t)h * HDIM;
#define EPI(ofv, dt) do { \
    _Pragma("unroll") \
    for (int _q = 0; _q < 4; ++_q) { \
      const int _col = (dt)*32 + 8*_q + 4*hi; \
      const unsigned int _w0 = cvtpk_bf16(ofv[4*_q+0]*inv, ofv[4*_q+1]*inv); \
      const unsigned int _w1 = cvtpk_bf16(ofv[4*_q+2]*inv, ofv[4*_q+3]*inv); \
      *(unsigned int*)(Crow + _col)     = _w0; \
      *(unsigned int*)(Crow + _col + 2) = _w1; \
    } } while(0)
  EPI(of0, 0);
  EPI(of1, 1);
  EPI(of2, 2);
  EPI(of3, 3);
#undef EPI
}

extern "C" void kernel_launch(void* const* d_in, const int* in_sizes, int n_in,
                              void* d_out, int out_size, void* d_ws, size_t ws_size,
                              hipStream_t stream)
{
  const float* hs   = (const float*)d_in[0];
  const float* rope = (const float*)d_in[1];
  const float* Wq   = (const float*)d_in[2];
  const float* bq   = (const float*)d_in[3];
  const float* Wk   = (const float*)d_in[4];
  const float* bk   = (const float*)d_in[5];
  const float* Wv   = (const float*)d_in[6];
  const float* bv   = (const float*)d_in[7];
  const float* Wo   = (const float*)d_in[8];

  char* ws = (char*)d_ws;
  const size_t MB = (size_t)1 << 20;
  // WkT/WvT contiguous: form stacked [512][4096] for the merged KV m97 GEMM
  unsigned short* Xbf  = (unsigned short*)(ws);             // 32MB
  unsigned short* Ctx  = Xbf;                               // alias: X dead after KV-GEMM
  unsigned short* WqT  = (unsigned short*)(ws + 32*MB);     // 32MB
  unsigned short* WkT  = (unsigned short*)(ws + 64*MB);     // 2MB
  unsigned short* WvT  = (unsigned short*)(ws + 66*MB);     // 2MB
  unsigned short* Qa   = WqT;                               // alias: WqT dead after Q-GEMM
  unsigned short* WoT  = (unsigned short*)(ws + 68*MB);     // 32MB
  unsigned short* Qtmp = (unsigned short*)(ws + 100*MB);    // 32MB
  unsigned short* KVt  = (unsigned short*)(ws + 132*MB);    // 4MB  [4096][512]
  unsigned short* Ka   = (unsigned short*)(ws + 136*MB);    // 2MB
  unsigned short* VTa  = (unsigned short*)(ws + 138*MB);    // 2MB -> total 140MB

  k_cast<<<(NT*HD/4 + 255)/256, 256, 0, stream>>>(hs, Xbf, NT*HD/4);

  dim3 tb(32, 32);
  k_transpose<<<dim3(HD/32,  HD/32), tb, 0, stream>>>(Wq, WqT, HD, HD);
  k_transpose<<<dim3(KVC/32, HD/32), tb, 0, stream>>>(Wk, WkT, HD, KVC);
  k_transpose<<<dim3(KVC/32, HD/32), tb, 0, stream>>>(Wv, WvT, HD, KVC);
  k_transpose<<<dim3(HD/32,  HD/32), tb, 0, stream>>>(Wo, WoT, HD, HD);

  // Q projection: 256^2 8-phase, grid 16x16 = 256 blocks (exactly 1 pass)
  k_gemm256<0><<<dim3(HD/256, NT/256), 512, 0, stream>>>(Xbf, WqT, bq, Qtmp, NT, HD, HD);
  // merged K|V projection: m97 128^2 kernel, grid 4x32 = 128 blocks, dual bias
  k_gemm<false><<<dim3(512/128, NT/128), 256, 0, stream>>>(Xbf, WkT, bk, bv, 256,
                                                           KVt, NT, 512, HD);

  // Q scale folds 1/sqrt(128) AND log2(e) (exp2-domain softmax)
  const float scq = 0.08838834764831845f * 1.4426950408889634f;
  k_rope<<<(NT*(HD/2)  + 255)/256, 256, 0, stream>>>(Qtmp, rope, Qa, HD, HD, NH, 11, scq);
  k_rope<<<(NT*(KVC/2) + 255)/256, 256, 0, stream>>>(KVt, rope, Ka, 512, KVC, NKV, 7, 1.0f);
  k_vt  <<<(NT*KVC     + 255)/256, 256, 0, stream>>>(KVt + 256, 512, VTa);

  // grid: (bh, qtile) so consecutive bids vary bh (fast) and each CU's block
  // set spans different qb values (work balance)
  k_attn<<<dim3(NH*BATCH, SEQ/128), 256, 0, stream>>>(Qa, Ka, VTa, Ctx);

  // O projection: 256^2 8-phase, f32 out, grid 256
  k_gemm256<1><<<dim3(HD/256, NT/256), 512, 0, stream>>>(Ctx, WoT, nullptr, d_out, NT, HD, HD);
}

// Round 17
// 534.846 us; speedup vs baseline: 1.0095x; 1.0095x over previous
//
#include <hip/hip_runtime.h>
#include <stdint.h>

#define SEQ   2048
#define BATCH 2
#define HD    4096
#define NH    32
#define NKV   2
#define HDIM  128
#define NT    (SEQ*BATCH)   // 4096 tokens
#define KVC   (NKV*HDIM)    // 256

typedef short  bf16x8 __attribute__((ext_vector_type(8)));
typedef short  sh4    __attribute__((ext_vector_type(4)));
typedef float  f32x4  __attribute__((ext_vector_type(4)));
typedef float  f32x16 __attribute__((ext_vector_type(16)));

__device__ __forceinline__ float bf2f(unsigned short u){
  union { unsigned int i; float f; } v; v.i = ((unsigned int)u) << 16; return v.f;
}
__device__ __forceinline__ unsigned short f2bf(float f){
  union { float f; unsigned int i; } v; v.f = f;
  unsigned int r = v.i + 0x7FFFu + ((v.i >> 16) & 1u);
  return (unsigned short)(r >> 16);
}
// pack 2 f32 -> 2 bf16 in one u32 (low = lo, high = hi)
__device__ __forceinline__ unsigned int cvtpk_bf16(float lo, float hi){
  unsigned int r;
  asm("v_cvt_pk_bf16_f32 %0, %1, %2" : "=v"(r) : "v"(lo), "v"(hi));
  return r;
}
// a[32:63] <-> b[0:31]
__device__ __forceinline__ void plane_swap(unsigned int &a, unsigned int &b){
  asm("v_permlane32_swap_b32 %0, %1" : "+v"(a), "+v"(b));
}
// Build PV B-frag (bf16x8) for one 16-k slice from 8 exp'd P values.
__device__ __forceinline__ bf16x8 mk_pf(float a0f,float a1f,float a2f,float a3f,
                                        float b0f,float b1f,float b2f,float b3f){
  unsigned int a0 = cvtpk_bf16(a0f, a1f);
  unsigned int a1 = cvtpk_bf16(a2f, a3f);
  unsigned int b0 = cvtpk_bf16(b0f, b1f);
  unsigned int b1 = cvtpk_bf16(b2f, b3f);
  plane_swap(a0, b0);
  plane_swap(a1, b1);
  union { unsigned int u[4]; bf16x8 h; } u;
  u.u[0] = a0; u.u[1] = a1; u.u[2] = b0; u.u[3] = b1;
  return u.h;
}

// async global->LDS, 16B per lane; LDS dest is wave-uniform base + lane*16
__device__ __forceinline__ void gload_lds16(const void* g, void* lds){
  __builtin_amdgcn_global_load_lds(
      (const __attribute__((address_space(1))) unsigned int*)(size_t)g,
      (__attribute__((address_space(3))) unsigned int*)(unsigned int)(size_t)lds,
      16, 0, 0);
}

__device__ __forceinline__ void BARRIER(){
  __builtin_amdgcn_sched_barrier(0);
  asm volatile("" ::: "memory");
  __builtin_amdgcn_s_barrier();
  asm volatile("" ::: "memory");
  __builtin_amdgcn_sched_barrier(0);
}
#define VMCNT(N) do { asm volatile("s_waitcnt vmcnt(" #N ")" ::: "memory"); \
                      __builtin_amdgcn_sched_barrier(0); } while(0)

// ---------------- cast fp32 -> bf16 (vectorized) ----------------
__global__ void k_cast(const float* __restrict__ in, unsigned short* __restrict__ out, int n4){
  int i = blockIdx.x * blockDim.x + threadIdx.x;
  if (i >= n4) return;
  float4 v = ((const float4*)in)[i];
  ushort4 o; o.x = f2bf(v.x); o.y = f2bf(v.y); o.z = f2bf(v.z); o.w = f2bf(v.w);
  ((ushort4*)out)[i] = o;
}

// ---------------- W (KxN fp32) -> W^T (NxK bf16), LDS tiled ----------------
__global__ void k_transpose(const float* __restrict__ W, unsigned short* __restrict__ WT,
                            int K, int N){
  __shared__ float t[32][33];
  int n0 = blockIdx.x * 32, k0 = blockIdx.y * 32;
  int tx = threadIdx.x, ty = threadIdx.y;
  t[ty][tx] = W[(size_t)(k0 + ty) * N + n0 + tx];
  __syncthreads();
  WT[(size_t)(n0 + ty) * K + k0 + tx] = f2bf(t[tx][ty]);
}

// ---------------- GEMM (m97 128x128) for small-N projections ----------------
// optional split bias: col < bsplit -> bias[col], else bias2[col-bsplit]
template<bool OUTF32>
__global__ __launch_bounds__(256) void k_gemm(
    const unsigned short* __restrict__ A,
    const unsigned short* __restrict__ BT,
    const float* __restrict__ bias,
    const float* __restrict__ bias2, int bsplit,
    void* __restrict__ C, int M, int N, int K)
{
  __shared__ unsigned short As[128*32];
  __shared__ unsigned short Bs[128*32];
  const int tid  = threadIdx.x;
  const int lane = tid & 63;
  const int w    = tid >> 6;
  const int l4   = lane >> 4, l15 = lane & 15;
  const int wm   = (w >> 1) * 64, wn = (w & 1) * 64;
  const size_t bm = (size_t)blockIdx.y * 128, bn = (size_t)blockIdx.x * 128;

  f32x4 acc[4][4] = {};
  const int scol = (lane & 3) * 8;

  for (int k0 = 0; k0 < K; k0 += 32) {
    #pragma unroll
    for (int j = 0; j < 2; ++j) {
      const int r = w*32 + j*16 + (lane >> 2);
      gload_lds16(A  + (bm + r) * (size_t)K + k0 + scol, As + (size_t)(w*32 + j*16) * 32);
      gload_lds16(BT + (bn + r) * (size_t)K + k0 + scol, Bs + (size_t)(w*32 + j*16) * 32);
    }
    __syncthreads();
    bf16x8 af[4], bfr[4];
    #pragma unroll
    for (int m = 0; m < 4; ++m)
      af[m] = *(const bf16x8*)(As + (wm + m*16 + l15)*32 + l4*8);
    #pragma unroll
    for (int n = 0; n < 4; ++n)
      bfr[n] = *(const bf16x8*)(Bs + (wn + n*16 + l15)*32 + l4*8);
    #pragma unroll
    for (int m = 0; m < 4; ++m)
      #pragma unroll
      for (int n = 0; n < 4; ++n)
        acc[m][n] = __builtin_amdgcn_mfma_f32_16x16x32_bf16(af[m], bfr[n], acc[m][n], 0, 0, 0);
    __syncthreads();
  }

  #pragma unroll
  for (int n = 0; n < 4; ++n) {
    const size_t col = bn + wn + n*16 + l15;
    float badd = 0.0f;
    if (bias) badd = (bias2 && (int)col >= bsplit) ? bias2[col - bsplit] : bias[col];
    #pragma unroll
    for (int m = 0; m < 4; ++m) {
      const size_t row0 = bm + wm + m*16 + l4*4;
      #pragma unroll
      for (int r = 0; r < 4; ++r) {
        float v = acc[m][n][r] + badd;
        if (OUTF32) ((float*)C)[(row0 + r) * (size_t)N + col] = v;
        else ((unsigned short*)C)[(row0 + r) * (size_t)N + col] = f2bf(v);
      }
    }
  }
}

// ---------------- 256x256 8-phase GEMM (T2+T3+T4+T5), K multiple of 128 ----------------
// MODE 0: bf16 out to C (ld N). MODE 1: f32 out to C (ld N).
template<int MODE>
__global__ __launch_bounds__(512, 2) void k_gemm256(
    const unsigned short* __restrict__ A,
    const unsigned short* __restrict__ BT,
    const float* __restrict__ bias,
    void* __restrict__ C,
    int M, int N, int K)
{
  __shared__ __attribute__((aligned(16))) unsigned short As[2][16384];
  __shared__ __attribute__((aligned(16))) unsigned short Bs[2][16384];
  const int tid  = threadIdx.x;
  const int lane = tid & 63;
  const int w    = tid >> 6;
  const int c    = lane & 15, g = lane >> 4;
  const int wm   = w >> 2, wn = w & 3;

  // XCD-aware mapping. For the 16x16 grid: each XCD (bid%8) owns a 4x8
  // rectangle of tiles -> per-XCD working set 8MB A + 16MB B.
  const int nwg = (int)(gridDim.x * gridDim.y);
  int bid = (int)(blockIdx.y * gridDim.x + blockIdx.x);
  int bx, by;
  if (gridDim.x == 16 && gridDim.y == 16) {
    const int k = bid & 7, cc = bid >> 3;     // XCD id, chunk index 0..31
    by = (k >> 1) * 4 + (cc >> 3);
    bx = (k & 1) * 8 + (cc & 7);
  } else {
    if ((nwg & 7) == 0) bid = (bid & 7) * (nwg >> 3) + (bid >> 3);
    bx = bid % (int)gridDim.x;
    by = bid / (int)gridDim.x;
  }
  const size_t bm = (size_t)by * 256, bn = (size_t)bx * 256;

  const char* Ab = (const char*)(A  + bm * (size_t)K);
  const char* Bb = (const char*)(BT + bn * (size_t)K);
  const size_t Kb2 = (size_t)K * 2;
  const int cswz = (c & 7) << 4;

  f32x4 acc[8][4] = {};
  bf16x8 af[4][2], bfr[4][2];

#define STAGE_A(bi, h, k0) do { \
    _Pragma("unroll") \
    for (int _j = 0; _j < 2; ++_j) { \
      const int _i = _j*512 + tid; \
      const int _row = (h)*128 + (_i >> 3); \
      const int _ch  = _i & 7; \
      gload_lds16(Ab + (size_t)_row * Kb2 + (size_t)(k0)*2 + ((_ch*16) ^ ((_row & 7) << 4)), \
                  (char*)As[bi] + (h)*16384 + _j*8192 + w*1024); \
    } } while(0)
#define STAGE_B(bi, h, k0) do { \
    _Pragma("unroll") \
    for (int _j = 0; _j < 2; ++_j) { \
      const int _i = _j*512 + tid; \
      const int _row = (h)*128 + (_i >> 3); \
      const int _ch  = _i & 7; \
      gload_lds16(Bb + (size_t)_row * Kb2 + (size_t)(k0)*2 + ((_ch*16) ^ ((_row & 7) << 4)), \
                  (char*)Bs[bi] + (h)*16384 + _j*8192 + w*1024); \
    } } while(0)
#define LDA(bi, mg) do { \
    _Pragma("unroll") \
    for (int _m = 0; _m < 4; ++_m) { \
      const char* _p = (const char*)As[bi] + (size_t)(((mg)*128 + _m*32 + wm*16 + c) * 128); \
      af[_m][0] = *(const bf16x8*)(_p + (( 0 + g*16) ^ cswz)); \
      af[_m][1] = *(const bf16x8*)(_p + ((64 + g*16) ^ cswz)); \
    } } while(0)
#define LDB(bi, ng) do { \
    _Pragma("unroll") \
    for (int _n = 0; _n < 2; ++_n) { \
      const char* _p = (const char*)Bs[bi] + (size_t)((((ng)*2+_n)*64 + wn*16 + c) * 128); \
      bfr[(ng)*2+_n][0] = *(const bf16x8*)(_p + (( 0 + g*16) ^ cswz)); \
      bfr[(ng)*2+_n][1] = *(const bf16x8*)(_p + ((64 + g*16) ^ cswz)); \
    } } while(0)
#define MFMA16(mg, ng) do { \
    __builtin_amdgcn_s_setprio(1); \
    _Pragma("unroll") \
    for (int _m = 0; _m < 4; ++_m) \
      _Pragma("unroll") \
      for (int _n = 0; _n < 2; ++_n) { \
        acc[(mg)*4+_m][(ng)*2+_n] = __builtin_amdgcn_mfma_f32_16x16x32_bf16( \
            af[_m][0], bfr[(ng)*2+_n][0], acc[(mg)*4+_m][(ng)*2+_n], 0, 0, 0); \
        acc[(mg)*4+_m][(ng)*2+_n] = __builtin_amdgcn_mfma_f32_16x16x32_bf16( \
            af[_m][1], bfr[(ng)*2+_n][1], acc[(mg)*4+_m][(ng)*2+_n], 0, 0, 0); \
      } \
    __builtin_amdgcn_s_setprio(0); \
  } while(0)

  STAGE_A(0, 0, 0);
  STAGE_B(0, 0, 0);
  STAGE_B(0, 1, 0);
  STAGE_A(0, 1, 0);
  STAGE_A(1, 0, 64);
  STAGE_B(1, 0, 64);
  VMCNT(8);
  BARRIER();

  const int niter = K >> 7;
  for (int it = 0; it < niter; ++it) {
    const int kb = it*128 + 64;
    int k2 = it*128 + 128; if (k2 >= K) k2 = 0;
    int k3 = it*128 + 192; if (k3 >= K) k3 = 0;
    // p1
    LDA(0, 0); LDB(0, 0);
    STAGE_A(1, 1, kb);
    BARRIER();
    MFMA16(0, 0);
    VMCNT(6);
    BARRIER();
    // p2
    LDB(0, 1);
    STAGE_B(1, 1, kb);
    BARRIER();
    MFMA16(0, 1);
    BARRIER();
    // p3
    LDA(0, 1);
    STAGE_A(0, 0, k2);
    BARRIER();
    MFMA16(1, 0);
    BARRIER();
    // p4
    STAGE_B(0, 0, k2);
    BARRIER();
    MFMA16(1, 1);
    VMCNT(8);
    BARRIER();
    // p5
    LDA(1, 0); LDB(1, 0);
    STAGE_A(0, 1, k2);
    BARRIER();
    MFMA16(0, 0);
    VMCNT(6);
    BARRIER();
    // p6
    LDB(1, 1);
    STAGE_B(0, 1, k2);
    BARRIER();
    MFMA16(0, 1);
    BARRIER();
    // p7
    LDA(1, 1);
    STAGE_A(1, 0, k3);
    BARRIER();
    MFMA16(1, 0);
    BARRIER();
    // p8
    STAGE_B(1, 0, k3);
    BARRIER();
    MFMA16(1, 1);
    VMCNT(8);
    BARRIER();
  }

  #pragma unroll
  for (int m = 0; m < 8; ++m) {
    const size_t row0 = bm + m*32 + wm*16 + g*4;
    #pragma unroll
    for (int n = 0; n < 4; ++n) {
      const int col = (int)bn + n*64 + wn*16 + c;
      const float badd = bias ? bias[col] : 0.0f;
      #pragma unroll
      for (int r = 0; r < 4; ++r) {
        float v = acc[m][n][r] + badd;
        if (MODE == 1) ((float*)C)[(row0 + r) * (size_t)N + col] = v;
        else ((unsigned short*)C)[(row0 + r) * (size_t)N + col] = f2bf(v);
      }
    }
  }
#undef STAGE_A
#undef STAGE_B
#undef LDA
#undef LDB
#undef MFMA16
}

// ---------------- RoPE + layout: [tok][ldin] -> [b][slab][s][d], optional scale ----------------
__global__ void k_rope(const unsigned short* __restrict__ In, const float* __restrict__ rope,
                       unsigned short* __restrict__ Out, int ldin, int ncols, int nslab,
                       int psh, float sc)
{
  int idx = blockIdx.x * 256 + threadIdx.x;
  int npair = ncols >> 1;
  if (idx >= NT * npair) return;
  int t = idx >> psh, pr = idx & (npair - 1);
  int colp = pr * 2, h = colp >> 7, d = colp & 127;
  int s = t >> 1, b = t & 1;
  float x0 = bf2f(In[(size_t)t * ldin + colp]);
  float x1 = bf2f(In[(size_t)t * ldin + colp + 1]);
  float o0 = x0, o1 = x1;
  if (d < 64) {
    int i2 = d >> 1;
    float cr = rope[((size_t)s * 32 + i2) * 2 + 0];
    float ci = rope[((size_t)s * 32 + i2) * 2 + 1];
    o0 = x0 * cr - x1 * ci;
    o1 = x1 * cr + x0 * ci;
  }
  size_t dst = ((size_t)(b * nslab + h) * SEQ + s) * HDIM + d;
  Out[dst]     = f2bf(o0 * sc);
  Out[dst + 1] = f2bf(o1 * sc);
}

// ---------------- V: [tok][ld] (256 cols) -> V^T [b][kv][d][s] ----------------
__global__ void k_vt(const unsigned short* __restrict__ In, int ld,
                     unsigned short* __restrict__ Out){
  int idx = blockIdx.x * 256 + threadIdx.x;
  if (idx >= NT * KVC) return;
  int t = idx >> 8, cp = idx & 255;
  int kv = cp >> 7, d = cp & 127;
  int s = t >> 1, b = t & 1;
  Out[((size_t)(b * NKV + kv) * HDIM + d) * SEQ + s] = In[(size_t)t * ld + cp];
}

// ---------------- causal flash attention: 32x32 MFMA, in-register softmax ----------------
// 4 waves/block, 32 q-rows/wave (QBLK=128), KVBLK=64. Swapped QK^T, T12/T13.
// launch_bounds(256,2): this kernel needs ~96 VGPR + 64 acc on the UNIFIED
// gfx950 register file — (256,4) caps waves at 128 total regs and spills the
// accumulator to scratch (r14: WRITE 32->248MB, 3x slower). Do not raise.
// Intra-block pipelining (dbuf r7 / counted-vmcnt r16) is NULL at 3 blocks/CU:
// cross-block TLP already hides stage latency. Keep single-buffer 2-barrier.
// Grid (bh, qtile): per-CU qb values span {c,c+4,c+8,c+12} -> balanced 1.43:1.
__global__ __launch_bounds__(256, 2) void k_attn(
    const unsigned short* __restrict__ Q,    // [b][h][s][d], pre-scaled log2e/sqrt(d)
    const unsigned short* __restrict__ Kk,   // [b][kv][s][d]
    const unsigned short* __restrict__ Vt,   // [b][kv][d][s]
    unsigned short* __restrict__ Ctx)        // [tok][4096]
{
  const int tid  = threadIdx.x;
  const int lane = tid & 63;
  const int w    = tid >> 6;
  const int l31  = lane & 31;                // q within wave tile; also t/d row idx
  const int hi   = lane >> 5;
  const int bh = (int)blockIdx.x;            // bh on x (fast dim)
  const int b = bh >> 5, h = bh & 31;
  const int qb = (int)(gridDim.y - 1 - blockIdx.y);  // big tiles dispatched first
  const int qw0 = qb * 128 + w * 32;

  const unsigned short* Qb = Q  + ((size_t)(b * NH  + h)        * SEQ + qw0) * HDIM;
  const char* Kb = (const char*)(Kk + ((size_t)(b * NKV + (h >> 4)) * SEQ) * HDIM);
  const char* Vb = (const char*)(Vt + ((size_t)(b * NKV + (h >> 4)) * HDIM) * SEQ);

  __shared__ unsigned short Ks[64*128];       // K tile [64 t][128 d], swizzled 256B rows
  __shared__ unsigned short Vs[128*64];       // V^T tile [128 d][64 t], swizzled 128B rows

  bf16x8 qf[8];
  #pragma unroll
  for (int kk = 0; kk < 8; ++kk)
    qf[kk] = *(const bf16x8*)(Qb + (size_t)l31 * HDIM + kk*16 + hi*8);

  f32x16 of0 = {}, of1 = {}, of2 = {}, of3 = {};
  float mrun = -1e30f, lrun = 0.0f;
  const int qmax = qw0 + 31;
  const int qg   = qw0 + l31;
  const int tblk = qb * 128 + 128;

  const int kr = lane >> 4, kc = lane & 15;   // K: 4 rows x 16 chunks
  const int vr = lane >> 3, vc = lane & 7;    // V: 8 rows x 8 chunks
  const int rswzK = (l31 & 15) << 4;          // K read-side XOR (4-bit)
  const int rswzV = (l31 & 7) << 4;           // V read-side XOR (3-bit)

  for (int t0 = 0; t0 < tblk; t0 += 64) {
    #pragma unroll
    for (int j = 0; j < 4; ++j) {
      const int r = w*16 + j*4 + kr;
      gload_lds16(Kb + (size_t)(t0 + r) * 256 + ((kc*16) ^ ((r & 15) << 4)),
                  (char*)Ks + (w*16 + j*4) * 256);
    }
    #pragma unroll
    for (int j = 0; j < 4; ++j) {
      const int d = w*32 + j*8 + vr;
      gload_lds16(Vb + (size_t)d * (SEQ*2) + (size_t)t0*2 + ((vc*16) ^ ((d & 7) << 4)),
                  (char*)Vs + (w*32 + j*8) * 128);
    }
    __syncthreads();

    if (t0 <= qmax) {                          // wave-uniform activity guard
      // ---- QK^T: s0 (t0..t0+31), s1 (t0+32..t0+63) ----
      f32x16 s0 = {};
      #pragma unroll
      for (int kk = 0; kk < 8; ++kk) {
        bf16x8 kf = *(const bf16x8*)((const char*)Ks + l31*256 + ((kk*32 + hi*16) ^ rswzK));
        s0 = __builtin_amdgcn_mfma_f32_32x32x16_bf16(kf, qf[kk], s0, 0, 0, 0);
      }
      const int qh0 = qg - t0 - 4*hi;
      if (t0 + 31 > qw0) {
        #pragma unroll
        for (int r = 0; r < 16; ++r) {
          const int tc = (r & 3) + 8*(r >> 2);
          if (tc > qh0) s0[r] = -1e30f;
        }
      }
      const bool act1 = (t0 + 32 <= qmax);
      f32x16 s1 = {};
      if (act1) {
        #pragma unroll
        for (int kk = 0; kk < 8; ++kk) {
          bf16x8 kf = *(const bf16x8*)((const char*)Ks + (32 + l31)*256 + ((kk*32 + hi*16) ^ rswzK));
          s1 = __builtin_amdgcn_mfma_f32_32x32x16_bf16(kf, qf[kk], s1, 0, 0, 0);
        }
        if (t0 + 63 > qw0) {
          const int qh1 = qh0 - 32;
          #pragma unroll
          for (int r = 0; r < 16; ++r) {
            const int tc = (r & 3) + 8*(r >> 2);
            if (tc > qh1) s1[r] = -1e30f;
          }
        }
      }
      // ---- in-register online softmax (exp2 domain), q = lane&31 ----
      float mloc = s0[0];
      #pragma unroll
      for (int r = 1; r < 16; ++r) mloc = fmaxf(mloc, s0[r]);
      if (act1) {
        #pragma unroll
        for (int r = 0; r < 16; ++r) mloc = fmaxf(mloc, s1[r]);
      }
      mloc = fmaxf(mloc, __shfl_xor(mloc, 32));
      if (!__all(mloc - mrun <= 8.0f)) {            // T13 defer-max
        const float mn = fmaxf(mrun, mloc);
        const float al = exp2f(mrun - mn);
        mrun = mn;
        lrun *= al;
        of0 *= al; of1 *= al; of2 *= al; of3 *= al;
      }
      float ps = 0.0f;
      float p0[16];
      #pragma unroll
      for (int r = 0; r < 16; ++r) { p0[r] = exp2f(s0[r] - mrun); ps += p0[r]; }
      const bf16x8 pf0 = mk_pf(p0[0],p0[1],p0[2],p0[3],   p0[4],p0[5],p0[6],p0[7]);
      const bf16x8 pf1 = mk_pf(p0[8],p0[9],p0[10],p0[11], p0[12],p0[13],p0[14],p0[15]);
      bf16x8 pf2, pf3;
      if (act1) {
        float p1[16];
        #pragma unroll
        for (int r = 0; r < 16; ++r) { p1[r] = exp2f(s1[r] - mrun); ps += p1[r]; }
        pf2 = mk_pf(p1[0],p1[1],p1[2],p1[3],   p1[4],p1[5],p1[6],p1[7]);
        pf3 = mk_pf(p1[8],p1[9],p1[10],p1[11], p1[12],p1[13],p1[14],p1[15]);
      }
      ps += __shfl_xor(ps, 32);
      lrun += ps;

      // ---- PV: O^T[d][q] += V^T-frag(A) x P-frag(B) ----
#define PVDT(ofv, dt) do { \
        const char* _vrow = (const char*)Vs + (size_t)(((dt)*32 + l31) * 128); \
        bf16x8 _v0 = *(const bf16x8*)(_vrow + (( 0 + hi*16) ^ rswzV)); \
        bf16x8 _v1 = *(const bf16x8*)(_vrow + ((32 + hi*16) ^ rswzV)); \
        ofv = __builtin_amdgcn_mfma_f32_32x32x16_bf16(_v0, pf0, ofv, 0, 0, 0); \
        ofv = __builtin_amdgcn_mfma_f32_32x32x16_bf16(_v1, pf1, ofv, 0, 0, 0); \
        if (act1) { \
          bf16x8 _v2 = *(const bf16x8*)(_vrow + ((64 + hi*16) ^ rswzV)); \
          bf16x8 _v3 = *(const bf16x8*)(_vrow + ((96 + hi*16) ^ rswzV)); \
          ofv = __builtin_amdgcn_mfma_f32_32x32x16_bf16(_v2, pf2, ofv, 0, 0, 0); \
          ofv = __builtin_amdgcn_mfma_f32_32x32x16_bf16(_v3, pf3, ofv, 0, 0, 0); \
        } } while(0)
      PVDT(of0, 0);
      PVDT(of1, 1);
      PVDT(of2, 2);
      PVDT(of3, 3);
#undef PVDT
    }
    __syncthreads();
  }

  // ---- epilogue: O^T -> Ctx. row s = qg; d = dt*32 + trow ----
  const float inv = 1.0f / lrun;
  unsigned short* Crow = Ctx + ((size_t)(qg * BATCH + b)) * HD + (size_t)h * HDIM;
#define EPI(ofv, dt) do { \
    _Pragma("unroll") \
    for (int _q = 0; _q < 4; ++_q) { \
      const int _col = (dt)*32 + 8*_q + 4*hi; \
      const unsigned int _w0 = cvtpk_bf16(ofv[4*_q+0]*inv, ofv[4*_q+1]*inv); \
      const unsigned int _w1 = cvtpk_bf16(ofv[4*_q+2]*inv, ofv[4*_q+3]*inv); \
      *(unsigned int*)(Crow + _col)     = _w0; \
      *(unsigned int*)(Crow + _col + 2) = _w1; \
    } } while(0)
  EPI(of0, 0);
  EPI(of1, 1);
  EPI(of2, 2);
  EPI(of3, 3);
#undef EPI
}

extern "C" void kernel_launch(void* const* d_in, const int* in_sizes, int n_in,
                              void* d_out, int out_size, void* d_ws, size_t ws_size,
                              hipStream_t stream)
{
  const float* hs   = (const float*)d_in[0];
  const float* rope = (const float*)d_in[1];
  const float* Wq   = (const float*)d_in[2];
  const float* bq   = (const float*)d_in[3];
  const float* Wk   = (const float*)d_in[4];
  const float* bk   = (const float*)d_in[5];
  const float* Wv   = (const float*)d_in[6];
  const float* bv   = (const float*)d_in[7];
  const float* Wo   = (const float*)d_in[8];

  char* ws = (char*)d_ws;
  const size_t MB = (size_t)1 << 20;
  // WkT/WvT contiguous: form stacked [512][4096] for the merged KV m97 GEMM
  unsigned short* Xbf  = (unsigned short*)(ws);             // 32MB
  unsigned short* Ctx  = Xbf;                               // alias: X dead after KV-GEMM
  unsigned short* WqT  = (unsigned short*)(ws + 32*MB);     // 32MB
  unsigned short* WkT  = (unsigned short*)(ws + 64*MB);     // 2MB
  unsigned short* WvT  = (unsigned short*)(ws + 66*MB);     // 2MB
  unsigned short* Qa   = WqT;                               // alias: WqT dead after Q-GEMM
  unsigned short* WoT  = (unsigned short*)(ws + 68*MB);     // 32MB
  unsigned short* Qtmp = (unsigned short*)(ws + 100*MB);    // 32MB
  unsigned short* KVt  = (unsigned short*)(ws + 132*MB);    // 4MB  [4096][512]
  unsigned short* Ka   = (unsigned short*)(ws + 136*MB);    // 2MB
  unsigned short* VTa  = (unsigned short*)(ws + 138*MB);    // 2MB -> total 140MB

  k_cast<<<(NT*HD/4 + 255)/256, 256, 0, stream>>>(hs, Xbf, NT*HD/4);

  dim3 tb(32, 32);
  k_transpose<<<dim3(HD/32,  HD/32), tb, 0, stream>>>(Wq, WqT, HD, HD);
  k_transpose<<<dim3(KVC/32, HD/32), tb, 0, stream>>>(Wk, WkT, HD, KVC);
  k_transpose<<<dim3(KVC/32, HD/32), tb, 0, stream>>>(Wv, WvT, HD, KVC);
  k_transpose<<<dim3(HD/32,  HD/32), tb, 0, stream>>>(Wo, WoT, HD, HD);

  // Q projection: 256^2 8-phase, grid 16x16 = 256 blocks (exactly 1 pass)
  k_gemm256<0><<<dim3(HD/256, NT/256), 512, 0, stream>>>(Xbf, WqT, bq, Qtmp, NT, HD, HD);
  // merged K|V projection: m97 128^2 kernel, grid 4x32 = 128 blocks, dual bias
  k_gemm<false><<<dim3(512/128, NT/128), 256, 0, stream>>>(Xbf, WkT, bk, bv, 256,
                                                           KVt, NT, 512, HD);

  // Q scale folds 1/sqrt(128) AND log2(e) (exp2-domain softmax)
  const float scq = 0.08838834764831845f * 1.4426950408889634f;
  k_rope<<<(NT*(HD/2)  + 255)/256, 256, 0, stream>>>(Qtmp, rope, Qa, HD, HD, NH, 11, scq);
  k_rope<<<(NT*(KVC/2) + 255)/256, 256, 0, stream>>>(KVt, rope, Ka, 512, KVC, NKV, 7, 1.0f);
  k_vt  <<<(NT*KVC     + 255)/256, 256, 0, stream>>>(KVt + 256, 512, VTa);

  // grid: (bh, qtile) so consecutive bids vary bh (fast) and each CU's block
  // set spans different qb values (work balance)
  k_attn<<<dim3(NH*BATCH, SEQ/128), 256, 0, stream>>>(Qa, Ka, VTa, Ctx);

  // O projection: 256^2 8-phase, f32 out, grid 256
  k_gemm256<1><<<dim3(HD/256, NT/256), 512, 0, stream>>>(Ctx, WoT, nullptr, d_out, NT, HD, HD);
}

// Round 18
// 533.191 us; speedup vs baseline: 1.0126x; 1.0031x over previous
//
#include <hip/hip_runtime.h>
#include <stdint.h>

#define SEQ   2048
#define BATCH 2
#define HD    4096
#define NH    32
#define NKV   2
#define HDIM  128
#define NT    (SEQ*BATCH)   // 4096 tokens
#define KVC   (NKV*HDIM)    // 256

typedef short  bf16x8 __attribute__((ext_vector_type(8)));
typedef short  sh4    __attribute__((ext_vector_type(4)));
typedef float  f32x4  __attribute__((ext_vector_type(4)));
typedef float  f32x16 __attribute__((ext_vector_type(16)));

__device__ __forceinline__ float bf2f(unsigned short u){
  union { unsigned int i; float f; } v; v.i = ((unsigned int)u) << 16; return v.f;
}
__device__ __forceinline__ unsigned short f2bf(float f){
  union { float f; unsigned int i; } v; v.f = f;
  unsigned int r = v.i + 0x7FFFu + ((v.i >> 16) & 1u);
  return (unsigned short)(r >> 16);
}
// pack 2 f32 -> 2 bf16 in one u32 (low = lo, high = hi)
__device__ __forceinline__ unsigned int cvtpk_bf16(float lo, float hi){
  unsigned int r;
  asm("v_cvt_pk_bf16_f32 %0, %1, %2" : "=v"(r) : "v"(lo), "v"(hi));
  return r;
}
// a[32:63] <-> b[0:31]
__device__ __forceinline__ void plane_swap(unsigned int &a, unsigned int &b){
  asm("v_permlane32_swap_b32 %0, %1" : "+v"(a), "+v"(b));
}
// Build PV B-frag (bf16x8) for one 16-k slice from 8 exp'd P values.
__device__ __forceinline__ bf16x8 mk_pf(float a0f,float a1f,float a2f,float a3f,
                                        float b0f,float b1f,float b2f,float b3f){
  unsigned int a0 = cvtpk_bf16(a0f, a1f);
  unsigned int a1 = cvtpk_bf16(a2f, a3f);
  unsigned int b0 = cvtpk_bf16(b0f, b1f);
  unsigned int b1 = cvtpk_bf16(b2f, b3f);
  plane_swap(a0, b0);
  plane_swap(a1, b1);
  union { unsigned int u[4]; bf16x8 h; } u;
  u.u[0] = a0; u.u[1] = a1; u.u[2] = b0; u.u[3] = b1;
  return u.h;
}

// async global->LDS, 16B per lane; LDS dest is wave-uniform base + lane*16
__device__ __forceinline__ void gload_lds16(const void* g, void* lds){
  __builtin_amdgcn_global_load_lds(
      (const __attribute__((address_space(1))) unsigned int*)(size_t)g,
      (__attribute__((address_space(3))) unsigned int*)(unsigned int)(size_t)lds,
      16, 0, 0);
}

// Plain barrier with memory-clobber fences only (no sched_barrier pinning —
// m141: blanket sched_barrier(0) defeats the compiler's scheduling, -40%).
// Memory ops (ds_read/ds_write/global_load_lds) cannot cross the clobber;
// register-only ops (MFMA drain, addr calc) stay schedulable.
__device__ __forceinline__ void BARRIER(){
  asm volatile("" ::: "memory");
  __builtin_amdgcn_s_barrier();
  asm volatile("" ::: "memory");
}
#define VMCNT(N) asm volatile("s_waitcnt vmcnt(" #N ")" ::: "memory")

// ---------------- cast fp32 -> bf16 (vectorized) ----------------
__global__ void k_cast(const float* __restrict__ in, unsigned short* __restrict__ out, int n4){
  int i = blockIdx.x * blockDim.x + threadIdx.x;
  if (i >= n4) return;
  float4 v = ((const float4*)in)[i];
  ushort4 o; o.x = f2bf(v.x); o.y = f2bf(v.y); o.z = f2bf(v.z); o.w = f2bf(v.w);
  ((ushort4*)out)[i] = o;
}

// ---------------- W (KxN fp32) -> W^T (NxK bf16), LDS tiled ----------------
__global__ void k_transpose(const float* __restrict__ W, unsigned short* __restrict__ WT,
                            int K, int N){
  __shared__ float t[32][33];
  int n0 = blockIdx.x * 32, k0 = blockIdx.y * 32;
  int tx = threadIdx.x, ty = threadIdx.y;
  t[ty][tx] = W[(size_t)(k0 + ty) * N + n0 + tx];
  __syncthreads();
  WT[(size_t)(n0 + ty) * K + k0 + tx] = f2bf(t[tx][ty]);
}

// ---------------- GEMM (m97 128x128) for small-N projections ----------------
// optional split bias: col < bsplit -> bias[col], else bias2[col-bsplit]
template<bool OUTF32>
__global__ __launch_bounds__(256) void k_gemm(
    const unsigned short* __restrict__ A,
    const unsigned short* __restrict__ BT,
    const float* __restrict__ bias,
    const float* __restrict__ bias2, int bsplit,
    void* __restrict__ C, int M, int N, int K)
{
  __shared__ unsigned short As[128*32];
  __shared__ unsigned short Bs[128*32];
  const int tid  = threadIdx.x;
  const int lane = tid & 63;
  const int w    = tid >> 6;
  const int l4   = lane >> 4, l15 = lane & 15;
  const int wm   = (w >> 1) * 64, wn = (w & 1) * 64;
  const size_t bm = (size_t)blockIdx.y * 128, bn = (size_t)blockIdx.x * 128;

  f32x4 acc[4][4] = {};
  const int scol = (lane & 3) * 8;

  for (int k0 = 0; k0 < K; k0 += 32) {
    #pragma unroll
    for (int j = 0; j < 2; ++j) {
      const int r = w*32 + j*16 + (lane >> 2);
      gload_lds16(A  + (bm + r) * (size_t)K + k0 + scol, As + (size_t)(w*32 + j*16) * 32);
      gload_lds16(BT + (bn + r) * (size_t)K + k0 + scol, Bs + (size_t)(w*32 + j*16) * 32);
    }
    __syncthreads();
    bf16x8 af[4], bfr[4];
    #pragma unroll
    for (int m = 0; m < 4; ++m)
      af[m] = *(const bf16x8*)(As + (wm + m*16 + l15)*32 + l4*8);
    #pragma unroll
    for (int n = 0; n < 4; ++n)
      bfr[n] = *(const bf16x8*)(Bs + (wn + n*16 + l15)*32 + l4*8);
    #pragma unroll
    for (int m = 0; m < 4; ++m)
      #pragma unroll
      for (int n = 0; n < 4; ++n)
        acc[m][n] = __builtin_amdgcn_mfma_f32_16x16x32_bf16(af[m], bfr[n], acc[m][n], 0, 0, 0);
    __syncthreads();
  }

  #pragma unroll
  for (int n = 0; n < 4; ++n) {
    const size_t col = bn + wn + n*16 + l15;
    float badd = 0.0f;
    if (bias) badd = (bias2 && (int)col >= bsplit) ? bias2[col - bsplit] : bias[col];
    #pragma unroll
    for (int m = 0; m < 4; ++m) {
      const size_t row0 = bm + wm + m*16 + l4*4;
      #pragma unroll
      for (int r = 0; r < 4; ++r) {
        float v = acc[m][n][r] + badd;
        if (OUTF32) ((float*)C)[(row0 + r) * (size_t)N + col] = v;
        else ((unsigned short*)C)[(row0 + r) * (size_t)N + col] = f2bf(v);
      }
    }
  }
}

// ---------------- 256x256 8-phase GEMM (T2+T3+T4+T5), K multiple of 128 ----------------
// MODE 0: bf16 out to C (ld N). MODE 1: f32 out to C (ld N).
template<int MODE>
__global__ __launch_bounds__(512, 2) void k_gemm256(
    const unsigned short* __restrict__ A,
    const unsigned short* __restrict__ BT,
    const float* __restrict__ bias,
    void* __restrict__ C,
    int M, int N, int K)
{
  __shared__ __attribute__((aligned(16))) unsigned short As[2][16384];
  __shared__ __attribute__((aligned(16))) unsigned short Bs[2][16384];
  const int tid  = threadIdx.x;
  const int lane = tid & 63;
  const int w    = tid >> 6;
  const int c    = lane & 15, g = lane >> 4;
  const int wm   = w >> 2, wn = w & 3;

  // XCD-aware mapping. For the 16x16 grid: each XCD (bid%8) owns a 4x8
  // rectangle of tiles -> per-XCD working set 8MB A + 16MB B.
  const int nwg = (int)(gridDim.x * gridDim.y);
  int bid = (int)(blockIdx.y * gridDim.x + blockIdx.x);
  int bx, by;
  if (gridDim.x == 16 && gridDim.y == 16) {
    const int k = bid & 7, cc = bid >> 3;     // XCD id, chunk index 0..31
    by = (k >> 1) * 4 + (cc >> 3);
    bx = (k & 1) * 8 + (cc & 7);
  } else {
    if ((nwg & 7) == 0) bid = (bid & 7) * (nwg >> 3) + (bid >> 3);
    bx = bid % (int)gridDim.x;
    by = bid / (int)gridDim.x;
  }
  const size_t bm = (size_t)by * 256, bn = (size_t)bx * 256;

  const char* Ab = (const char*)(A  + bm * (size_t)K);
  const char* Bb = (const char*)(BT + bn * (size_t)K);
  const size_t Kb2 = (size_t)K * 2;
  const int cswz = (c & 7) << 4;

  f32x4 acc[8][4] = {};
  bf16x8 af[4][2], bfr[4][2];

#define STAGE_A(bi, h, k0) do { \
    _Pragma("unroll") \
    for (int _j = 0; _j < 2; ++_j) { \
      const int _i = _j*512 + tid; \
      const int _row = (h)*128 + (_i >> 3); \
      const int _ch  = _i & 7; \
      gload_lds16(Ab + (size_t)_row * Kb2 + (size_t)(k0)*2 + ((_ch*16) ^ ((_row & 7) << 4)), \
                  (char*)As[bi] + (h)*16384 + _j*8192 + w*1024); \
    } } while(0)
#define STAGE_B(bi, h, k0) do { \
    _Pragma("unroll") \
    for (int _j = 0; _j < 2; ++_j) { \
      const int _i = _j*512 + tid; \
      const int _row = (h)*128 + (_i >> 3); \
      const int _ch  = _i & 7; \
      gload_lds16(Bb + (size_t)_row * Kb2 + (size_t)(k0)*2 + ((_ch*16) ^ ((_row & 7) << 4)), \
                  (char*)Bs[bi] + (h)*16384 + _j*8192 + w*1024); \
    } } while(0)
#define LDA(bi, mg) do { \
    _Pragma("unroll") \
    for (int _m = 0; _m < 4; ++_m) { \
      const char* _p = (const char*)As[bi] + (size_t)(((mg)*128 + _m*32 + wm*16 + c) * 128); \
      af[_m][0] = *(const bf16x8*)(_p + (( 0 + g*16) ^ cswz)); \
      af[_m][1] = *(const bf16x8*)(_p + ((64 + g*16) ^ cswz)); \
    } } while(0)
#define LDB(bi, ng) do { \
    _Pragma("unroll") \
    for (int _n = 0; _n < 2; ++_n) { \
      const char* _p = (const char*)Bs[bi] + (size_t)((((ng)*2+_n)*64 + wn*16 + c) * 128); \
      bfr[(ng)*2+_n][0] = *(const bf16x8*)(_p + (( 0 + g*16) ^ cswz)); \
      bfr[(ng)*2+_n][1] = *(const bf16x8*)(_p + ((64 + g*16) ^ cswz)); \
    } } while(0)
#define MFMA16(mg, ng) do { \
    __builtin_amdgcn_s_setprio(1); \
    _Pragma("unroll") \
    for (int _m = 0; _m < 4; ++_m) \
      _Pragma("unroll") \
      for (int _n = 0; _n < 2; ++_n) { \
        acc[(mg)*4+_m][(ng)*2+_n] = __builtin_amdgcn_mfma_f32_16x16x32_bf16( \
            af[_m][0], bfr[(ng)*2+_n][0], acc[(mg)*4+_m][(ng)*2+_n], 0, 0, 0); \
        acc[(mg)*4+_m][(ng)*2+_n] = __builtin_amdgcn_mfma_f32_16x16x32_bf16( \
            af[_m][1], bfr[(ng)*2+_n][1], acc[(mg)*4+_m][(ng)*2+_n], 0, 0, 0); \
      } \
    __builtin_amdgcn_s_setprio(0); \
  } while(0)

  STAGE_A(0, 0, 0);
  STAGE_B(0, 0, 0);
  STAGE_B(0, 1, 0);
  STAGE_A(0, 1, 0);
  STAGE_A(1, 0, 64);
  STAGE_B(1, 0, 64);
  VMCNT(8);
  BARRIER();

  const int niter = K >> 7;
  for (int it = 0; it < niter; ++it) {
    const int kb = it*128 + 64;
    int k2 = it*128 + 128; if (k2 >= K) k2 = 0;
    int k3 = it*128 + 192; if (k3 >= K) k3 = 0;
    // p1
    LDA(0, 0); LDB(0, 0);
    STAGE_A(1, 1, kb);
    BARRIER();
    MFMA16(0, 0);
    VMCNT(6);
    BARRIER();
    // p2
    LDB(0, 1);
    STAGE_B(1, 1, kb);
    BARRIER();
    MFMA16(0, 1);
    BARRIER();
    // p3
    LDA(0, 1);
    STAGE_A(0, 0, k2);
    BARRIER();
    MFMA16(1, 0);
    BARRIER();
    // p4
    STAGE_B(0, 0, k2);
    BARRIER();
    MFMA16(1, 1);
    VMCNT(8);
    BARRIER();
    // p5
    LDA(1, 0); LDB(1, 0);
    STAGE_A(0, 1, k2);
    BARRIER();
    MFMA16(0, 0);
    VMCNT(6);
    BARRIER();
    // p6
    LDB(1, 1);
    STAGE_B(0, 1, k2);
    BARRIER();
    MFMA16(0, 1);
    BARRIER();
    // p7
    LDA(1, 1);
    STAGE_A(1, 0, k3);
    BARRIER();
    MFMA16(1, 0);
    BARRIER();
    // p8
    STAGE_B(1, 0, k3);
    BARRIER();
    MFMA16(1, 1);
    VMCNT(8);
    BARRIER();
  }

  #pragma unroll
  for (int m = 0; m < 8; ++m) {
    const size_t row0 = bm + m*32 + wm*16 + g*4;
    #pragma unroll
    for (int n = 0; n < 4; ++n) {
      const int col = (int)bn + n*64 + wn*16 + c;
      const float badd = bias ? bias[col] : 0.0f;
      #pragma unroll
      for (int r = 0; r < 4; ++r) {
        float v = acc[m][n][r] + badd;
        if (MODE == 1) ((float*)C)[(row0 + r) * (size_t)N + col] = v;
        else ((unsigned short*)C)[(row0 + r) * (size_t)N + col] = f2bf(v);
      }
    }
  }
#undef STAGE_A
#undef STAGE_B
#undef LDA
#undef LDB
#undef MFMA16
}

// ---------------- RoPE + layout: [tok][ldin] -> [b][slab][s][d], optional scale ----------------
__global__ void k_rope(const unsigned short* __restrict__ In, const float* __restrict__ rope,
                       unsigned short* __restrict__ Out, int ldin, int ncols, int nslab,
                       int psh, float sc)
{
  int idx = blockIdx.x * 256 + threadIdx.x;
  int npair = ncols >> 1;
  if (idx >= NT * npair) return;
  int t = idx >> psh, pr = idx & (npair - 1);
  int colp = pr * 2, h = colp >> 7, d = colp & 127;
  int s = t >> 1, b = t & 1;
  float x0 = bf2f(In[(size_t)t * ldin + colp]);
  float x1 = bf2f(In[(size_t)t * ldin + colp + 1]);
  float o0 = x0, o1 = x1;
  if (d < 64) {
    int i2 = d >> 1;
    float cr = rope[((size_t)s * 32 + i2) * 2 + 0];
    float ci = rope[((size_t)s * 32 + i2) * 2 + 1];
    o0 = x0 * cr - x1 * ci;
    o1 = x1 * cr + x0 * ci;
  }
  size_t dst = ((size_t)(b * nslab + h) * SEQ + s) * HDIM + d;
  Out[dst]     = f2bf(o0 * sc);
  Out[dst + 1] = f2bf(o1 * sc);
}

// ---------------- V: [tok][ld] (256 cols) -> V^T [b][kv][d][s] ----------------
__global__ void k_vt(const unsigned short* __restrict__ In, int ld,
                     unsigned short* __restrict__ Out){
  int idx = blockIdx.x * 256 + threadIdx.x;
  if (idx >= NT * KVC) return;
  int t = idx >> 8, cp = idx & 255;
  int kv = cp >> 7, d = cp & 127;
  int s = t >> 1, b = t & 1;
  Out[((size_t)(b * NKV + kv) * HDIM + d) * SEQ + s] = In[(size_t)t * ld + cp];
}

// ---------------- causal flash attention: 32x32 MFMA, in-register softmax ----------------
// 4 waves/block, 32 q-rows/wave (QBLK=128), KVBLK=64. Swapped QK^T, T12/T13.
// launch_bounds(256,2): this kernel needs ~96 VGPR + 64 acc on the UNIFIED
// gfx950 register file — (256,4) caps waves at 128 total regs and spills the
// accumulator to scratch (r14: WRITE 32->248MB, 3x slower). Do not raise.
// Intra-block pipelining (dbuf r7 / counted-vmcnt r16) is NULL at 3 blocks/CU:
// cross-block TLP already hides stage latency. Keep single-buffer 2-barrier.
// Grid (bh, qtile): per-CU qb values span {c,c+4,c+8,c+12} -> balanced 1.43:1.
__global__ __launch_bounds__(256, 2) void k_attn(
    const unsigned short* __restrict__ Q,    // [b][h][s][d], pre-scaled log2e/sqrt(d)
    const unsigned short* __restrict__ Kk,   // [b][kv][s][d]
    const unsigned short* __restrict__ Vt,   // [b][kv][d][s]
    unsigned short* __restrict__ Ctx)        // [tok][4096]
{
  const int tid  = threadIdx.x;
  const int lane = tid & 63;
  const int w    = tid >> 6;
  const int l31  = lane & 31;                // q within wave tile; also t/d row idx
  const int hi   = lane >> 5;
  const int bh = (int)blockIdx.x;            // bh on x (fast dim)
  const int b = bh >> 5, h = bh & 31;
  const int qb = (int)(gridDim.y - 1 - blockIdx.y);  // big tiles dispatched first
  const int qw0 = qb * 128 + w * 32;

  const unsigned short* Qb = Q  + ((size_t)(b * NH  + h)        * SEQ + qw0) * HDIM;
  const char* Kb = (const char*)(Kk + ((size_t)(b * NKV + (h >> 4)) * SEQ) * HDIM);
  const char* Vb = (const char*)(Vt + ((size_t)(b * NKV + (h >> 4)) * HDIM) * SEQ);

  __shared__ unsigned short Ks[64*128];       // K tile [64 t][128 d], swizzled 256B rows
  __shared__ unsigned short Vs[128*64];       // V^T tile [128 d][64 t], swizzled 128B rows

  bf16x8 qf[8];
  #pragma unroll
  for (int kk = 0; kk < 8; ++kk)
    qf[kk] = *(const bf16x8*)(Qb + (size_t)l31 * HDIM + kk*16 + hi*8);

  f32x16 of0 = {}, of1 = {}, of2 = {}, of3 = {};
  float mrun = -1e30f, lrun = 0.0f;
  const int qmax = qw0 + 31;
  const int qg   = qw0 + l31;
  const int tblk = qb * 128 + 128;

  const int kr = lane >> 4, kc = lane & 15;   // K: 4 rows x 16 chunks
  const int vr = lane >> 3, vc = lane & 7;    // V: 8 rows x 8 chunks
  const int rswzK = (l31 & 15) << 4;          // K read-side XOR (4-bit)
  const int rswzV = (l31 & 7) << 4;           // V read-side XOR (3-bit)

  for (int t0 = 0; t0 < tblk; t0 += 64) {
    #pragma unroll
    for (int j = 0; j < 4; ++j) {
      const int r = w*16 + j*4 + kr;
      gload_lds16(Kb + (size_t)(t0 + r) * 256 + ((kc*16) ^ ((r & 15) << 4)),
                  (char*)Ks + (w*16 + j*4) * 256);
    }
    #pragma unroll
    for (int j = 0; j < 4; ++j) {
      const int d = w*32 + j*8 + vr;
      gload_lds16(Vb + (size_t)d * (SEQ*2) + (size_t)t0*2 + ((vc*16) ^ ((d & 7) << 4)),
                  (char*)Vs + (w*32 + j*8) * 128);
    }
    __syncthreads();

    if (t0 <= qmax) {                          // wave-uniform activity guard
      // ---- QK^T: s0 (t0..t0+31), s1 (t0+32..t0+63) ----
      f32x16 s0 = {};
      #pragma unroll
      for (int kk = 0; kk < 8; ++kk) {
        bf16x8 kf = *(const bf16x8*)((const char*)Ks + l31*256 + ((kk*32 + hi*16) ^ rswzK));
        s0 = __builtin_amdgcn_mfma_f32_32x32x16_bf16(kf, qf[kk], s0, 0, 0, 0);
      }
      const int qh0 = qg - t0 - 4*hi;
      if (t0 + 31 > qw0) {
        #pragma unroll
        for (int r = 0; r < 16; ++r) {
          const int tc = (r & 3) + 8*(r >> 2);
          if (tc > qh0) s0[r] = -1e30f;
        }
      }
      const bool act1 = (t0 + 32 <= qmax);
      f32x16 s1 = {};
      if (act1) {
        #pragma unroll
        for (int kk = 0; kk < 8; ++kk) {
          bf16x8 kf = *(const bf16x8*)((const char*)Ks + (32 + l31)*256 + ((kk*32 + hi*16) ^ rswzK));
          s1 = __builtin_amdgcn_mfma_f32_32x32x16_bf16(kf, qf[kk], s1, 0, 0, 0);
        }
        if (t0 + 63 > qw0) {
          const int qh1 = qh0 - 32;
          #pragma unroll
          for (int r = 0; r < 16; ++r) {
            const int tc = (r & 3) + 8*(r >> 2);
            if (tc > qh1) s1[r] = -1e30f;
          }
        }
      }
      // ---- in-register online softmax (exp2 domain), q = lane&31 ----
      float mloc = s0[0];
      #pragma unroll
      for (int r = 1; r < 16; ++r) mloc = fmaxf(mloc, s0[r]);
      if (act1) {
        #pragma unroll
        for (int r = 0; r < 16; ++r) mloc = fmaxf(mloc, s1[r]);
      }
      mloc = fmaxf(mloc, __shfl_xor(mloc, 32));
      if (!__all(mloc - mrun <= 8.0f)) {            // T13 defer-max
        const float mn = fmaxf(mrun, mloc);
        const float al = exp2f(mrun - mn);
        mrun = mn;
        lrun *= al;
        of0 *= al; of1 *= al; of2 *= al; of3 *= al;
      }
      float ps = 0.0f;
      float p0[16];
      #pragma unroll
      for (int r = 0; r < 16; ++r) { p0[r] = exp2f(s0[r] - mrun); ps += p0[r]; }
      const bf16x8 pf0 = mk_pf(p0[0],p0[1],p0[2],p0[3],   p0[4],p0[5],p0[6],p0[7]);
      const bf16x8 pf1 = mk_pf(p0[8],p0[9],p0[10],p0[11], p0[12],p0[13],p0[14],p0[15]);
      bf16x8 pf2, pf3;
      if (act1) {
        float p1[16];
        #pragma unroll
        for (int r = 0; r < 16; ++r) { p1[r] = exp2f(s1[r] - mrun); ps += p1[r]; }
        pf2 = mk_pf(p1[0],p1[1],p1[2],p1[3],   p1[4],p1[5],p1[6],p1[7]);
        pf3 = mk_pf(p1[8],p1[9],p1[10],p1[11], p1[12],p1[13],p1[14],p1[15]);
      }
      ps += __shfl_xor(ps, 32);
      lrun += ps;

      // ---- PV: O^T[d][q] += V^T-frag(A) x P-frag(B) ----
#define PVDT(ofv, dt) do { \
        const char* _vrow = (const char*)Vs + (size_t)(((dt)*32 + l31) * 128); \
        bf16x8 _v0 = *(const bf16x8*)(_vrow + (( 0 + hi*16) ^ rswzV)); \
        bf16x8 _v1 = *(const bf16x8*)(_vrow + ((32 + hi*16) ^ rswzV)); \
        ofv = __builtin_amdgcn_mfma_f32_32x32x16_bf16(_v0, pf0, ofv, 0, 0, 0); \
        ofv = __builtin_amdgcn_mfma_f32_32x32x16_bf16(_v1, pf1, ofv, 0, 0, 0); \
        if (act1) { \
          bf16x8 _v2 = *(const bf16x8*)(_vrow + ((64 + hi*16) ^ rswzV)); \
          bf16x8 _v3 = *(const bf16x8*)(_vrow + ((96 + hi*16) ^ rswzV)); \
          ofv = __builtin_amdgcn_mfma_f32_32x32x16_bf16(_v2, pf2, ofv, 0, 0, 0); \
          ofv = __builtin_amdgcn_mfma_f32_32x32x16_bf16(_v3, pf3, ofv, 0, 0, 0); \
        } } while(0)
      PVDT(of0, 0);
      PVDT(of1, 1);
      PVDT(of2, 2);
      PVDT(of3, 3);
#undef PVDT
    }
    __syncthreads();
  }

  // ---- epilogue: O^T -> Ctx. row s = qg; d = dt*32 + trow ----
  const float inv = 1.0f / lrun;
  unsigned short* Crow = Ctx + ((size_t)(qg * BATCH + b)) * HD + (size_t)h * HDIM;
#define EPI(ofv, dt) do { \
    _Pragma("unroll") \
    for (int _q = 0; _q < 4; ++_q) { \
      const int _col = (dt)*32 + 8*_q + 4*hi; \
      const unsigned int _w0 = cvtpk_bf16(ofv[4*_q+0]*inv, ofv[4*_q+1]*inv); \
      const unsigned int _w1 = cvtpk_bf16(ofv[4*_q+2]*inv, ofv[4*_q+3]*inv); \
      *(unsigned int*)(Crow + _col)     = _w0; \
      *(unsigned int*)(Crow + _col + 2) = _w1; \
    } } while(0)
  EPI(of0, 0);
  EPI(of1, 1);
  EPI(of2, 2);
  EPI(of3, 3);
#undef EPI
}

extern "C" void kernel_launch(void* const* d_in, const int* in_sizes, int n_in,
                              void* d_out, int out_size, void* d_ws, size_t ws_size,
                              hipStream_t stream)
{
  const float* hs   = (const float*)d_in[0];
  const float* rope = (const float*)d_in[1];
  const float* Wq   = (const float*)d_in[2];
  const float* bq   = (const float*)d_in[3];
  const float* Wk   = (const float*)d_in[4];
  const float* bk   = (const float*)d_in[5];
  const float* Wv   = (const float*)d_in[6];
  const float* bv   = (const float*)d_in[7];
  const float* Wo   = (const float*)d_in[8];

  char* ws = (char*)d_ws;
  const size_t MB = (size_t)1 << 20;
  // WkT/WvT contiguous: form stacked [512][4096] for the merged KV m97 GEMM
  unsigned short* Xbf  = (unsigned short*)(ws);             // 32MB
  unsigned short* Ctx  = Xbf;                               // alias: X dead after KV-GEMM
  unsigned short* WqT  = (unsigned short*)(ws + 32*MB);     // 32MB
  unsigned short* WkT  = (unsigned short*)(ws + 64*MB);     // 2MB
  unsigned short* WvT  = (unsigned short*)(ws + 66*MB);     // 2MB
  unsigned short* Qa   = WqT;                               // alias: WqT dead after Q-GEMM
  unsigned short* WoT  = (unsigned short*)(ws + 68*MB);     // 32MB
  unsigned short* Qtmp = (unsigned short*)(ws + 100*MB);    // 32MB
  unsigned short* KVt  = (unsigned short*)(ws + 132*MB);    // 4MB  [4096][512]
  unsigned short* Ka   = (unsigned short*)(ws + 136*MB);    // 2MB
  unsigned short* VTa  = (unsigned short*)(ws + 138*MB);    // 2MB -> total 140MB

  k_cast<<<(NT*HD/4 + 255)/256, 256, 0, stream>>>(hs, Xbf, NT*HD/4);

  dim3 tb(32, 32);
  k_transpose<<<dim3(HD/32,  HD/32), tb, 0, stream>>>(Wq, WqT, HD, HD);
  k_transpose<<<dim3(KVC/32, HD/32), tb, 0, stream>>>(Wk, WkT, HD, KVC);
  k_transpose<<<dim3(KVC/32, HD/32), tb, 0, stream>>>(Wv, WvT, HD, KVC);
  k_transpose<<<dim3(HD/32,  HD/32), tb, 0, stream>>>(Wo, WoT, HD, HD);

  // Q projection: 256^2 8-phase, grid 16x16 = 256 blocks (exactly 1 pass)
  k_gemm256<0><<<dim3(HD/256, NT/256), 512, 0, stream>>>(Xbf, WqT, bq, Qtmp, NT, HD, HD);
  // merged K|V projection: m97 128^2 kernel, grid 4x32 = 128 blocks, dual bias
  k_gemm<false><<<dim3(512/128, NT/128), 256, 0, stream>>>(Xbf, WkT, bk, bv, 256,
                                                           KVt, NT, 512, HD);

  // Q scale folds 1/sqrt(128) AND log2(e) (exp2-domain softmax)
  const float scq = 0.08838834764831845f * 1.4426950408889634f;
  k_rope<<<(NT*(HD/2)  + 255)/256, 256, 0, stream>>>(Qtmp, rope, Qa, HD, HD, NH, 11, scq);
  k_rope<<<(NT*(KVC/2) + 255)/256, 256, 0, stream>>>(KVt, rope, Ka, 512, KVC, NKV, 7, 1.0f);
  k_vt  <<<(NT*KVC     + 255)/256, 256, 0, stream>>>(KVt + 256, 512, VTa);

  // grid: (bh, qtile) so consecutive bids vary bh (fast) and each CU's block
  // set spans different qb values (work balance)
  k_attn<<<dim3(NH*BATCH, SEQ/128), 256, 0, stream>>>(Qa, Ka, VTa, Ctx);

  // O projection: 256^2 8-phase, f32 out, grid 256
  k_gemm256<1><<<dim3(HD/256, NT/256), 512, 0, stream>>>(Ctx, WoT, nullptr, d_out, NT, HD, HD);
}